// Round 3
// baseline (97.077 us; speedup 1.0000x reference)
//
#include <hip/hip_runtime.h>

// QConv2d factored: out[(c,pxpy),(cs,qxqy)] = sum_{c1,c2} uc[c][c1+2] uc[cs][c2+2] *
//   (ux,uy contracted on all four spatial axes of rho block (c1,c2)).
// v3: grid 1024, block = (batch b, out-channel c). Each block computes all four
// 64x64 W blocks (wave w = (c1,c2), lane = (px,qx); 8x8 in-register fiber over
// (py,qy); one padded intra-wave LDS transpose) but writes only channel c's 64KB
// slice. 2 resident blocks/CU, 4/CU over lifetime -> store/compute pipelining.
// Blocks of one batch map to the same XCD (blk%8 const) -> rho re-read hits L2.

#define TPB 256

__global__ __launch_bounds__(TPB, 2) void qconv_fused(
    const float* __restrict__ rho,   // [256][128][128]
    const float* __restrict__ ux,    // [8][8]
    const float* __restrict__ uy,    // [8][8]
    const float* __restrict__ uc,    // [4][4]
    float* __restrict__ out)         // [256][256][256]
{
    __shared__ alignas(16) float L[4][64][68];  // 69632 B: transpose / W-exchange

    const int tid  = threadIdx.x;
    const int w    = tid >> 6;          // wave id: c1 = w>>1, c2 = w&1
    const int lane = tid & 63;
    const int c1   = w >> 1, c2 = w & 1;
    const int px   = lane >> 3, qx = lane & 7;

    const int blk = blockIdx.x;
    const int b   = ((blk >> 5) << 3) | (blk & 7);  // batch
    const int c   = (blk >> 3) & 3;                 // output channel this block writes

    const float* rb = rho + (size_t)b * 16384 + (size_t)((c1 << 6) + (px << 3)) * 128
                      + (c2 << 6) + (qx << 3);

    float X[64], Y[64];

    // ---- load X[py][qy] = rho_blk[(px,py),(qx,qy)] : 16 x b128
#pragma unroll
    for (int py = 0; py < 8; ++py) {
        float4 lo = *(const float4*)(rb + py * 128);
        float4 hi = *(const float4*)(rb + py * 128 + 4);
        X[py * 8 + 0] = lo.x; X[py * 8 + 1] = lo.y; X[py * 8 + 2] = lo.z; X[py * 8 + 3] = lo.w;
        X[py * 8 + 4] = hi.x; X[py * 8 + 5] = hi.y; X[py * 8 + 6] = hi.z; X[py * 8 + 7] = hi.w;
    }

    // ---- phase A (qy first: row-local, lets FMAs start as rows arrive):
    // Y[py][j] = sum_k X[py][k] * uy[j][k]
#pragma unroll
    for (int py = 0; py < 8; ++py) {
#pragma unroll
        for (int j = 0; j < 8; ++j) {
            float acc = 0.f;
#pragma unroll
            for (int k = 0; k < 8; ++k) acc += uy[j * 8 + k] * X[py * 8 + k];
            Y[py * 8 + j] = acc;
        }
    }
    // X[i][j] = sum_k uy[i][k] * Y[k][j]   (py contraction)
#pragma unroll
    for (int i = 0; i < 8; ++i) {
#pragma unroll
        for (int j = 0; j < 8; ++j) {
            float acc = 0.f;
#pragma unroll
            for (int k = 0; k < 8; ++k) acc += uy[i * 8 + k] * Y[k * 8 + j];
            X[i * 8 + j] = acc;
        }
    }

    // ---- intra-wave transpose: (in-thread py',qy') <-> (lane px,qx)
#pragma unroll
    for (int e = 0; e < 64; ++e) L[w][e][lane] = X[e];   // lanes contiguous: conflict-free
    __syncthreads();
#pragma unroll
    for (int f4 = 0; f4 < 16; ++f4) {                    // row read, stride 68: <=2-way
        float4 v = *(const float4*)&L[w][lane][f4 * 4];
        X[f4 * 4 + 0] = v.x; X[f4 * 4 + 1] = v.y; X[f4 * 4 + 2] = v.z; X[f4 * 4 + 3] = v.w;
    }
    // now thread identity: (py',qy') = (lane>>3, lane&7); X[px][qx]

    // ---- phase B (qx then px, with ux)
#pragma unroll
    for (int p = 0; p < 8; ++p) {
#pragma unroll
        for (int j = 0; j < 8; ++j) {
            float acc = 0.f;
#pragma unroll
            for (int k = 0; k < 8; ++k) acc += ux[j * 8 + k] * X[p * 8 + k];
            Y[p * 8 + j] = acc;
        }
    }
#pragma unroll
    for (int i = 0; i < 8; ++i) {
#pragma unroll
        for (int j = 0; j < 8; ++j) {
            float acc = 0.f;
#pragma unroll
            for (int k = 0; k < 8; ++k) acc += ux[i * 8 + k] * Y[k * 8 + j];
            X[i * 8 + j] = acc;
        }
    }
    // X[px'][qx'] = W_{c1,c2}[(px',py'),(qx',qy')]

    __syncthreads();  // all transpose reads of L done before overwrite

    // ---- W exchange: spatial-row-major layout L[w][px'*8+py'][qx'*8+qy']
    {
        const int pyp = lane >> 3, qyp = lane & 7;
#pragma unroll
        for (int px_ = 0; px_ < 8; ++px_)
#pragma unroll
            for (int qx_ = 0; qx_ < 8; ++qx_)
                L[w][px_ * 8 + pyp][qx_ * 8 + qyp] = X[px_ * 8 + qx_];  // <=2-way: free
    }
    __syncthreads();

    // ---- epilogue: this block writes only channel c (64 rows x 256 cols)
    const float e0 = uc[c * 4 + 2], e1 = uc[c * 4 + 3];
    float a2[4][2];
#pragma unroll
    for (int cs = 0; cs < 4; ++cs) { a2[cs][0] = uc[cs * 4 + 2]; a2[cs][1] = uc[cs * 4 + 3]; }

    float* ob = out + (size_t)b * 65536;
#pragma unroll
    for (int i = 0; i < 4; ++i) {
        const int g  = tid + 256 * i;
        const int sp = g >> 4;          // spatial row px'*8+py' (16i..16i+15)
        const int qg = g & 15;          // 4-col group
        float4 wv[4];
#pragma unroll
        for (int ww = 0; ww < 4; ++ww) wv[ww] = *(const float4*)&L[ww][sp][qg * 4];
#pragma unroll
        for (int cs = 0; cs < 4; ++cs) {
            const float k00 = e0 * a2[cs][0], k01 = e0 * a2[cs][1];
            const float k10 = e1 * a2[cs][0], k11 = e1 * a2[cs][1];
            float4 v;
            v.x = k00 * wv[0].x + k01 * wv[1].x + k10 * wv[2].x + k11 * wv[3].x;
            v.y = k00 * wv[0].y + k01 * wv[1].y + k10 * wv[2].y + k11 * wv[3].y;
            v.z = k00 * wv[0].z + k01 * wv[1].z + k10 * wv[2].z + k11 * wv[3].z;
            v.w = k00 * wv[0].w + k01 * wv[1].w + k10 * wv[2].w + k11 * wv[3].w;
            *(float4*)&ob[(size_t)((c * 64 + sp) * 256 + cs * 64 + qg * 4)] = v;
        }
    }
}

extern "C" void kernel_launch(void* const* d_in, const int* in_sizes, int n_in,
                              void* d_out, int out_size, void* d_ws, size_t ws_size,
                              hipStream_t stream) {
    const float* rho = (const float*)d_in[0];
    const float* ux  = (const float*)d_in[1];
    const float* uy  = (const float*)d_in[2];
    const float* uc  = (const float*)d_in[3];
    float* out = (float*)d_out;
    qconv_fused<<<dim3(1024), dim3(TPB), 0, stream>>>(rho, ux, uy, uc, out);
}

// Round 4
// 90.141 us; speedup vs baseline: 1.0769x; 1.0769x over previous
//
#include <hip/hip_runtime.h>

// QConv2d v4: wave-specialized, zero-redundancy.
// Grid 256 (1 block/CU = batch b), TPB 512 (8 waves).
// Waves 0-3: each computes W_{c1,c2} = (ux(x)uy) rho_blk (ux(x)uy)^T exactly once
//   (lane=(px,qx), 8x8 reg fiber over (py,qy); wave-private LDS transpose, no barrier).
// One __syncthreads, then all 8 waves combine channels + store 256 KB.
// rho read 16 MiB total (no redundancy), out write 64 MiB -> 12.8 us roofline.

#define TPB 512

__global__ __launch_bounds__(TPB, 2) void qconv_fused(
    const float* __restrict__ rho,   // [256][128][128]
    const float* __restrict__ ux,    // [8][8]
    const float* __restrict__ uy,    // [8][8]
    const float* __restrict__ uc,    // [4][4]
    float* __restrict__ out)         // [256][256][256]
{
    __shared__ alignas(16) float L[4][64][68];  // 69632 B; slice [w] is wave-private until barrier

    const int tid = threadIdx.x;
    const int b   = blockIdx.x;

    if (tid < 256) {  // producer waves 0-3 (whole waves: no intra-wave divergence)
        const int w    = tid >> 6;          // (c1,c2) = (w>>1, w&1)
        const int lane = tid & 63;
        const int c1   = w >> 1, c2 = w & 1;
        const int px   = lane >> 3, qx = lane & 7;

        const float* rb = rho + (size_t)b * 16384
                        + (size_t)((c1 << 6) + (px << 3)) * 128 + (c2 << 6) + (qx << 3);

        float X[64], Y[64];

        // load X[py][qy] = rho_blk[(px,py),(qx,qy)] : 16 x b128
#pragma unroll
        for (int py = 0; py < 8; ++py) {
            float4 lo = *(const float4*)(rb + py * 128);
            float4 hi = *(const float4*)(rb + py * 128 + 4);
            X[py*8+0]=lo.x; X[py*8+1]=lo.y; X[py*8+2]=lo.z; X[py*8+3]=lo.w;
            X[py*8+4]=hi.x; X[py*8+5]=hi.y; X[py*8+6]=hi.z; X[py*8+7]=hi.w;
        }

        // phase A: contract qy (row-local; FMAs start as rows arrive), then py
#pragma unroll
        for (int py = 0; py < 8; ++py)
#pragma unroll
            for (int j = 0; j < 8; ++j) {
                float acc = 0.f;
#pragma unroll
                for (int k = 0; k < 8; ++k) acc += uy[j*8+k] * X[py*8+k];
                Y[py*8+j] = acc;
            }
#pragma unroll
        for (int i = 0; i < 8; ++i)
#pragma unroll
            for (int j = 0; j < 8; ++j) {
                float acc = 0.f;
#pragma unroll
                for (int k = 0; k < 8; ++k) acc += uy[i*8+k] * Y[k*8+j];
                X[i*8+j] = acc;
            }

        // wave-private transpose: (in-thread py',qy') <-> (lane px,qx)
#pragma unroll
        for (int e = 0; e < 64; ++e) L[w][e][lane] = X[e];       // conflict-free
        __asm__ volatile("s_waitcnt lgkmcnt(0)" ::: "memory");   // DS in-order per wave + drain
#pragma unroll
        for (int f4 = 0; f4 < 16; ++f4) {
            float4 v = *(const float4*)&L[w][lane][f4 * 4];
            X[f4*4+0]=v.x; X[f4*4+1]=v.y; X[f4*4+2]=v.z; X[f4*4+3]=v.w;
        }
        // now thread identity (py',qy') = (lane>>3, lane&7); X[px][qx]

        // phase B: contract qx then px with ux
#pragma unroll
        for (int p = 0; p < 8; ++p)
#pragma unroll
            for (int j = 0; j < 8; ++j) {
                float acc = 0.f;
#pragma unroll
                for (int k = 0; k < 8; ++k) acc += ux[j*8+k] * X[p*8+k];
                Y[p*8+j] = acc;
            }
#pragma unroll
        for (int i = 0; i < 8; ++i)
#pragma unroll
            for (int j = 0; j < 8; ++j) {
                float acc = 0.f;
#pragma unroll
                for (int k = 0; k < 8; ++k) acc += ux[i*8+k] * Y[k*8+j];
                X[i*8+j] = acc;
            }
        // X[px'][qx'] = W_{c1,c2}[(px',py'),(qx',qy')]

        // W exchange (overwrites own wave's slice; reads above already returned):
        // layout L[w][px'*8+py'][qx'*8+qy']   (<=2-way banks: free)
        {
            const int pyp = lane >> 3, qyp = lane & 7;
#pragma unroll
            for (int px_ = 0; px_ < 8; ++px_)
#pragma unroll
                for (int qx_ = 0; qx_ < 8; ++qx_)
                    L[w][px_*8+pyp][qx_*8+qyp] = X[px_*8+qx_];
        }
    }

    __syncthreads();  // producers done -> all 8 waves store

    // epilogue: 512 threads split 4 c x 64 sp x 16 qg x 4 cs = 16384 float4 stores
    float e0[4], e1[4];
#pragma unroll
    for (int c = 0; c < 4; ++c) { e0[c] = uc[c*4+2]; e1[c] = uc[c*4+3]; }

    float* ob = out + (size_t)b * 65536;
#pragma unroll
    for (int i = 0; i < 2; ++i) {
        const int g  = tid + TPB * i;   // 0..1023
        const int sp = g >> 4;          // spatial row px'*8+py'
        const int qg = g & 15;          // 4-col group
        float4 wv[4];
#pragma unroll
        for (int ww = 0; ww < 4; ++ww) wv[ww] = *(const float4*)&L[ww][sp][qg * 4];
#pragma unroll
        for (int c = 0; c < 4; ++c) {
#pragma unroll
            for (int cs = 0; cs < 4; ++cs) {
                const float k00 = e0[c]*e0[cs], k01 = e0[c]*e1[cs];
                const float k10 = e1[c]*e0[cs], k11 = e1[c]*e1[cs];
                float4 v;
                v.x = k00*wv[0].x + k01*wv[1].x + k10*wv[2].x + k11*wv[3].x;
                v.y = k00*wv[0].y + k01*wv[1].y + k10*wv[2].y + k11*wv[3].y;
                v.z = k00*wv[0].z + k01*wv[1].z + k10*wv[2].z + k11*wv[3].z;
                v.w = k00*wv[0].w + k01*wv[1].w + k10*wv[2].w + k11*wv[3].w;
                *(float4*)&ob[(size_t)((c*64 + sp) * 256 + cs*64 + qg*4)] = v;
            }
        }
    }
}

extern "C" void kernel_launch(void* const* d_in, const int* in_sizes, int n_in,
                              void* d_out, int out_size, void* d_ws, size_t ws_size,
                              hipStream_t stream) {
    const float* rho = (const float*)d_in[0];
    const float* ux  = (const float*)d_in[1];
    const float* uy  = (const float*)d_in[2];
    const float* uc  = (const float*)d_in[3];
    float* out = (float*)d_out;
    qconv_fused<<<dim3(256), dim3(TPB), 0, stream>>>(rho, ux, uy, uc, out);
}

// Round 5
// 88.903 us; speedup vs baseline: 1.0919x; 1.0139x over previous
//
#include <hip/hip_runtime.h>

// QConv2d v5: zero-redundancy + strip-mined epilogue (stores overlap compute).
// Grid 256 (1 block/CU = batch), TPB 512 (8 waves).
// Waves 0-3 (producers): load rho block (c1,c2), contract qy,py (uy), wave-private
//   LDS transpose, contract qx (ux) -> Y[px][qx'] in regs. Then 4 strips: compute
//   2 rows (px') of W, write to LDS slice, barrier; ALL 8 waves store that 64 KB
//   out-strip while producers compute the next strip. Strips hit disjoint LDS rows
//   -> 1 barrier/strip, stores spread over kernel lifetime instead of one tail burst.

#define TPB 512

__global__ __launch_bounds__(TPB, 2) void qconv_fused(
    const float* __restrict__ rho,   // [256][128][128]
    const float* __restrict__ ux,    // [8][8]
    const float* __restrict__ uy,    // [8][8]
    const float* __restrict__ uc,    // [4][4]
    float* __restrict__ out)         // [256][256][256]
{
    __shared__ alignas(16) float L[4][64][68];  // 69632 B; slice [w] wave-private pre-barrier

    const int tid  = threadIdx.x;
    const int b    = blockIdx.x;
    const int w    = tid >> 6;
    const int lane = tid & 63;
    const int pyp  = lane >> 3, qyp = lane & 7;   // producer post-transpose identity

    // epilogue work identity (all threads): 512 = 16 qg x 2 cs-half x 16 sp-local
    const int qg  = tid & 15;
    const int csh = (tid >> 4) & 1;
    const int spl = tid >> 5;                     // 0..15

    float e0[4], e1[4];
#pragma unroll
    for (int c = 0; c < 4; ++c) { e0[c] = uc[c*4+2]; e1[c] = uc[c*4+3]; }
    float* ob = out + (size_t)b * 65536;

    float Y[64];  // producers: Y[px][qx'] after B1; live through strip loop

    if (w < 4) {  // producer waves (whole waves, no intra-wave divergence)
        const int c1 = w >> 1, c2 = w & 1;
        const int px = lane >> 3, qx = lane & 7;
        const float* rb = rho + (size_t)b * 16384
                        + (size_t)((c1 << 6) + (px << 3)) * 128 + (c2 << 6) + (qx << 3);

        float X[64];
        // load X[py][qy]: 16 x b128
#pragma unroll
        for (int py = 0; py < 8; ++py) {
            float4 lo = *(const float4*)(rb + py * 128);
            float4 hi = *(const float4*)(rb + py * 128 + 4);
            X[py*8+0]=lo.x; X[py*8+1]=lo.y; X[py*8+2]=lo.z; X[py*8+3]=lo.w;
            X[py*8+4]=hi.x; X[py*8+5]=hi.y; X[py*8+6]=hi.z; X[py*8+7]=hi.w;
        }
        // contract qy (row-local: FMAs start as rows arrive)
#pragma unroll
        for (int py = 0; py < 8; ++py)
#pragma unroll
            for (int j = 0; j < 8; ++j) {
                float acc = 0.f;
#pragma unroll
                for (int k = 0; k < 8; ++k) acc += uy[j*8+k] * X[py*8+k];
                Y[py*8+j] = acc;
            }
        // contract py
#pragma unroll
        for (int i = 0; i < 8; ++i)
#pragma unroll
            for (int j = 0; j < 8; ++j) {
                float acc = 0.f;
#pragma unroll
                for (int k = 0; k < 8; ++k) acc += uy[i*8+k] * Y[k*8+j];
                X[i*8+j] = acc;
            }
        // wave-private transpose: (in-thread py',qy') <-> (lane px,qx)
#pragma unroll
        for (int e = 0; e < 64; ++e) L[w][e][lane] = X[e];       // conflict-free
        __asm__ volatile("s_waitcnt lgkmcnt(0)" ::: "memory");   // DS in-order per wave
#pragma unroll
        for (int f4 = 0; f4 < 16; ++f4) {
            float4 v = *(const float4*)&L[w][lane][f4 * 4];
            X[f4*4+0]=v.x; X[f4*4+1]=v.y; X[f4*4+2]=v.z; X[f4*4+3]=v.w;
        }
        // contract qx: Y[px][qx'] = sum_k ux[qx'][k] X[px][k]
#pragma unroll
        for (int p = 0; p < 8; ++p)
#pragma unroll
            for (int j = 0; j < 8; ++j) {
                float acc = 0.f;
#pragma unroll
                for (int k = 0; k < 8; ++k) acc += ux[j*8+k] * X[p*8+k];
                Y[p*8+j] = acc;
            }
    }

    // strip loop: producers finish W rows 2s,2s+1; everyone stores strip s (sp in [16s,16s+16))
#pragma unroll
    for (int s = 0; s < 4; ++s) {
        if (w < 4) {
#pragma unroll
            for (int i2 = 0; i2 < 2; ++i2) {
                const int i = 2*s + i2;   // px'
#pragma unroll
                for (int j = 0; j < 8; ++j) {
                    float acc = 0.f;
#pragma unroll
                    for (int k = 0; k < 8; ++k) acc += ux[i*8+k] * Y[k*8+j];
                    L[w][i*8+pyp][j*8+qyp] = acc;   // <=2-way banks: free
                }
            }
        }
        __syncthreads();  // strip s W visible to all waves (disjoint rows vs other strips)

        const int sp = 16*s + spl;
        float4 wv[4];
#pragma unroll
        for (int ww = 0; ww < 4; ++ww) wv[ww] = *(const float4*)&L[ww][sp][qg * 4];
#pragma unroll
        for (int c = 0; c < 4; ++c) {
#pragma unroll
            for (int cs2 = 0; cs2 < 2; ++cs2) {
                const int cs = 2*csh + cs2;
                const float k00 = e0[c]*e0[cs], k01 = e0[c]*e1[cs];
                const float k10 = e1[c]*e0[cs], k11 = e1[c]*e1[cs];
                float4 v;
                v.x = k00*wv[0].x + k01*wv[1].x + k10*wv[2].x + k11*wv[3].x;
                v.y = k00*wv[0].y + k01*wv[1].y + k10*wv[2].y + k11*wv[3].y;
                v.z = k00*wv[0].z + k01*wv[1].z + k10*wv[2].z + k11*wv[3].z;
                v.w = k00*wv[0].w + k01*wv[1].w + k10*wv[2].w + k11*wv[3].w;
                *(float4*)&ob[(size_t)((c*64 + sp) * 256 + cs*64 + qg*4)] = v;
            }
        }
    }
}

extern "C" void kernel_launch(void* const* d_in, const int* in_sizes, int n_in,
                              void* d_out, int out_size, void* d_ws, size_t ws_size,
                              hipStream_t stream) {
    const float* rho = (const float*)d_in[0];
    const float* ux  = (const float*)d_in[1];
    const float* uy  = (const float*)d_in[2];
    const float* uc  = (const float*)d_in[3];
    float* out = (float*)d_out;
    qconv_fused<<<dim3(256), dim3(TPB), 0, stream>>>(rho, ux, uy, uc, out);
}